// Round 3
// baseline (130.491 us; speedup 1.0000x reference)
//
#include <hip/hip_runtime.h>

#define BATCH 131072
#define IN 128
#define OUT 128
#define PNUM 16
#define GRID 512
#define ITERS 8          // GRID * 32 rows/block-iter * ITERS == BATCH

typedef _Float16 f16x8 __attribute__((ext_vector_type(8)));
typedef float f32x4 __attribute__((ext_vector_type(4)));

__device__ __forceinline__ float tanh_fast(float v) {
    float e = __expf(2.0f * v);
    return 1.0f - 2.0f * __builtin_amdgcn_rcpf(e + 1.0f);
}

// w[o*IN + i] = (f16) sum_p coef[o][i][p]; 64B contiguous per thread, coalesced.
__global__ __launch_bounds__(256) void prep_w_kernel(const float* __restrict__ coef,
                                                     _Float16* __restrict__ w) {
    int t = blockIdx.x * blockDim.x + threadIdx.x;
    const float4* p = (const float4*)(coef + (size_t)t * PNUM);
    float4 a = p[0], b = p[1], c = p[2], d = p[3];
    float s = (a.x + a.y + a.z + a.w) + (b.x + b.y + b.z + b.w)
            + (c.x + c.y + c.z + c.w) + (d.x + d.y + d.z + d.w);
    w[t] = (_Float16)s;
}

// Barrier-free streaming GEMM. Block = 256 (4 waves).
// Wave tile: 16 rows x 64 cols; wv>>1 picks row-group, wv&1 picks col-half.
// B (w) fragments live in VGPRs for the whole kernel (L2-resident source).
// 8-iteration row loop with next-iter x prefetch in flight during compute.
__global__ __launch_bounds__(256, 2) void gemm_tanh_kernel(const float* __restrict__ x,
                                                           const _Float16* __restrict__ w,
                                                           const float* __restrict__ trange,
                                                           float* __restrict__ out) {
    const float t = trange[0];
    const int lane = threadIdx.x & 63;
    const int wv   = threadIdx.x >> 6;
    const int m  = lane & 15;
    const int q  = lane >> 4;
    const int rg = wv >> 1;          // row group 0/1
    const int ch = wv & 1;           // col half 0/1

    // B-frag[nt][ks]: lane holds B[k = ks*32 + q*8 + j][n = ch*64 + nt*16 + m] = w[n][k]
    f16x8 bf[4][4];
#pragma unroll
    for (int nt = 0; nt < 4; ++nt)
#pragma unroll
        for (int ks = 0; ks < 4; ++ks)
            bf[nt][ks] = *(const f16x8*)(w + (size_t)(ch * 64 + nt * 16 + m) * IN + ks * 32 + q * 8);

    const size_t row0 = (size_t)blockIdx.x * 32 + rg * 16;

    // prefetch iteration 0 (lane reads 32B contiguous per ks: k = ks*32+q*8 .. +7)
    float4 xv[8];
    {
        const float* xr = x + (row0 + m) * IN;
#pragma unroll
        for (int ks = 0; ks < 4; ++ks) {
            xv[2 * ks]     = *(const float4*)(xr + ks * 32 + q * 8);
            xv[2 * ks + 1] = *(const float4*)(xr + ks * 32 + q * 8 + 4);
        }
    }

#pragma unroll
    for (int i = 0; i < ITERS; ++i) {
        // consume xv -> A fragments (f16)
        f16x8 af[4];
#pragma unroll
        for (int ks = 0; ks < 4; ++ks) {
            float4 a = xv[2 * ks], b = xv[2 * ks + 1];
            af[ks][0] = (_Float16)tanh_fast(a.x * t);
            af[ks][1] = (_Float16)tanh_fast(a.y * t);
            af[ks][2] = (_Float16)tanh_fast(a.z * t);
            af[ks][3] = (_Float16)tanh_fast(a.w * t);
            af[ks][4] = (_Float16)tanh_fast(b.x * t);
            af[ks][5] = (_Float16)tanh_fast(b.y * t);
            af[ks][6] = (_Float16)tanh_fast(b.z * t);
            af[ks][7] = (_Float16)tanh_fast(b.w * t);
        }

        // issue next-iter prefetch (xv free after af); overlaps MFMA + stores
        if (i + 1 < ITERS) {
            const float* xn = x + (row0 + (size_t)(i + 1) * (GRID * 32) + m) * IN;
#pragma unroll
            for (int ks = 0; ks < 4; ++ks) {
                xv[2 * ks]     = *(const float4*)(xn + ks * 32 + q * 8);
                xv[2 * ks + 1] = *(const float4*)(xn + ks * 32 + q * 8 + 4);
            }
        }

        // 16 MFMAs: 4 col-tiles x 4 k-steps
        f32x4 acc[4];
#pragma unroll
        for (int nt = 0; nt < 4; ++nt) acc[nt] = (f32x4){0.f, 0.f, 0.f, 0.f};
#pragma unroll
        for (int ks = 0; ks < 4; ++ks)
#pragma unroll
            for (int nt = 0; nt < 4; ++nt)
                acc[nt] = __builtin_amdgcn_mfma_f32_16x16x32_f16(af[ks], bf[nt][ks], acc[nt], 0, 0, 0);

        // store 16 rows x 64 cols (dword per lane; 64B segments per quarter-wave)
        float* orow = out + (row0 + (size_t)i * (GRID * 32) + q * 4) * OUT + ch * 64 + m;
#pragma unroll
        for (int nt = 0; nt < 4; ++nt)
#pragma unroll
            for (int r = 0; r < 4; ++r)
                orow[(size_t)r * OUT + nt * 16] = acc[nt][r];
    }
}

extern "C" void kernel_launch(void* const* d_in, const int* in_sizes, int n_in,
                              void* d_out, int out_size, void* d_ws, size_t ws_size,
                              hipStream_t stream) {
    const float* x    = (const float*)d_in[0];
    const float* coef = (const float*)d_in[1];
    const float* tr   = (const float*)d_in[2];
    float* out = (float*)d_out;
    _Float16* w = (_Float16*)d_ws;   // 32 KB scratch, L2-resident

    prep_w_kernel<<<(OUT * IN) / 256, 256, 0, stream>>>(coef, w);
    gemm_tanh_kernel<<<GRID, 256, 0, stream>>>(x, w, tr, out);
}

// Round 4
// 124.379 us; speedup vs baseline: 1.0491x; 1.0491x over previous
//
#include <hip/hip_runtime.h>

#define BATCH 131072
#define IN 128
#define OUT 128
#define PNUM 16
#define GRID 1024
#define ITERS 2            // GRID * 64 * ITERS == BATCH
#define LDS_PITCH 132      // f16; start-bank pattern = uniform 8 touches/bank (min)

typedef _Float16 f16x8 __attribute__((ext_vector_type(8)));
typedef float f32x4 __attribute__((ext_vector_type(4)));

__device__ __forceinline__ float tanh_fast(float v) {
    float e = __expf(2.0f * v);
    return 1.0f - 2.0f * __builtin_amdgcn_rcpf(e + 1.0f);
}

// w[o*IN + i] = (f16) sum_p coef[o][i][p]; 64B contiguous per thread, coalesced.
__global__ __launch_bounds__(256) void prep_w_kernel(const float* __restrict__ coef,
                                                     _Float16* __restrict__ w) {
    int t = blockIdx.x * blockDim.x + threadIdx.x;
    const float4* p = (const float4*)(coef + (size_t)t * PNUM);
    float4 a = p[0], b = p[1], c = p[2], d = p[3];
    float s = (a.x + a.y + a.z + a.w) + (b.x + b.y + b.z + b.w)
            + (c.x + c.y + c.z + c.w) + (d.x + d.y + d.z + d.w);
    w[t] = (_Float16)s;
}

// Block = 256 (4 waves). Wave = 16 rows x all 128 cols (tanh computed once/elem).
// w staged to padded LDS once per block; 2-iter row loop with x prefetch in
// flight during MFMA+store. Grid 1024 = 4 blocks/CU resident -> 16 waves/CU.
__global__ __launch_bounds__(256, 4) void gemm_tanh_kernel(const float* __restrict__ x,
                                                           const _Float16* __restrict__ w,
                                                           const float* __restrict__ trange,
                                                           float* __restrict__ out) {
    __shared__ _Float16 wlds[OUT * LDS_PITCH];

    const float t = trange[0];
    const int tid  = threadIdx.x;
    const int lane = tid & 63;
    const int rg   = tid >> 6;       // wave = row group 0..3
    const int m = lane & 15;
    const int q = lane >> 4;

    const size_t blk_row = (size_t)blockIdx.x * (64 * ITERS);

    // issue iter-0 x prefetch first (longest dependency chain)
    float4 xv[8];
    {
        const float* xr = x + (blk_row + rg * 16 + m) * IN;
#pragma unroll
        for (int ks = 0; ks < 4; ++ks) {
            xv[2 * ks]     = *(const float4*)(xr + ks * 32 + q * 8);
            xv[2 * ks + 1] = *(const float4*)(xr + ks * 32 + q * 8 + 4);
        }
    }

    // stage w (32 KB, L2-resident) into padded LDS; 64 f16 per thread
#pragma unroll
    for (int j = 0; j < 8; ++j) {
        int idx = (j * 256 + tid) * 8;
        int r = idx >> 7;
        int c = idx & 127;
        *(f16x8*)&wlds[r * LDS_PITCH + c] = *(const f16x8*)(w + idx);
    }
    __syncthreads();

#pragma unroll
    for (int i = 0; i < ITERS; ++i) {
        // consume xv -> A fragments (tanh once per element)
        f16x8 af[4];
#pragma unroll
        for (int ks = 0; ks < 4; ++ks) {
            float4 a = xv[2 * ks], b = xv[2 * ks + 1];
            af[ks][0] = (_Float16)tanh_fast(a.x * t);
            af[ks][1] = (_Float16)tanh_fast(a.y * t);
            af[ks][2] = (_Float16)tanh_fast(a.z * t);
            af[ks][3] = (_Float16)tanh_fast(a.w * t);
            af[ks][4] = (_Float16)tanh_fast(b.x * t);
            af[ks][5] = (_Float16)tanh_fast(b.y * t);
            af[ks][6] = (_Float16)tanh_fast(b.z * t);
            af[ks][7] = (_Float16)tanh_fast(b.w * t);
        }

        // issue next-iter x prefetch; stays in flight through MFMA + stores
        if (i + 1 < ITERS) {
            const float* xn = x + (blk_row + (i + 1) * 64 + rg * 16 + m) * IN;
#pragma unroll
            for (int ks = 0; ks < 4; ++ks) {
                xv[2 * ks]     = *(const float4*)(xn + ks * 32 + q * 8);
                xv[2 * ks + 1] = *(const float4*)(xn + ks * 32 + q * 8 + 4);
            }
        }

        // 32 MFMAs: 8 col-tiles x 4 k-steps; B from LDS (ds_read_b128)
        f32x4 acc[8];
#pragma unroll
        for (int nt = 0; nt < 8; ++nt) acc[nt] = (f32x4){0.f, 0.f, 0.f, 0.f};
#pragma unroll
        for (int ks = 0; ks < 4; ++ks) {
            const int kb = ks * 32 + q * 8;
#pragma unroll
            for (int nt = 0; nt < 8; ++nt) {
                f16x8 bf = *(const f16x8*)&wlds[(nt * 16 + m) * LDS_PITCH + kb];
                acc[nt] = __builtin_amdgcn_mfma_f32_16x16x32_f16(af[ks], bf, acc[nt], 0, 0, 0);
            }
        }

        // store 16 rows x 128 cols (64B segments per quarter-wave)
        float* orow = out + (blk_row + (size_t)i * 64 + rg * 16 + q * 4) * OUT + m;
#pragma unroll
        for (int nt = 0; nt < 8; ++nt)
#pragma unroll
            for (int r = 0; r < 4; ++r)
                orow[(size_t)r * OUT + nt * 16] = acc[nt][r];
    }
}

extern "C" void kernel_launch(void* const* d_in, const int* in_sizes, int n_in,
                              void* d_out, int out_size, void* d_ws, size_t ws_size,
                              hipStream_t stream) {
    const float* x    = (const float*)d_in[0];
    const float* coef = (const float*)d_in[1];
    const float* tr   = (const float*)d_in[2];
    float* out = (float*)d_out;
    _Float16* w = (_Float16*)d_ws;   // 32 KB scratch, L2-resident

    prep_w_kernel<<<(OUT * IN) / 256, 256, 0, stream>>>(coef, w);
    gemm_tanh_kernel<<<GRID, 256, 0, stream>>>(x, w, tr, out);
}